// Round 2
// baseline (605.640 us; speedup 1.0000x reference)
//
#include <hip/hip_runtime.h>
#include <hip/hip_bf16.h>

using bf16x8 = __attribute__((ext_vector_type(8))) __bf16;
using bf16x4 = __attribute__((ext_vector_type(4))) __bf16;
using f32x4  = __attribute__((ext_vector_type(4))) float;

constexpr int T_SEQ = 4096;
constexpr int HID_C = 2048;
constexpr int NH    = 16;
constexpr int QKV_N = 6144;
constexpr int CHUNK = 128;

__device__ __forceinline__ float head_slope(int h) {
    // slope[h] = -2^{-(h+1)/2} * (1 - 1/31 + 1e-5)
    return -exp2f(-0.5f * (float)(h + 1)) * 0.967751935483871f;
}

__device__ __forceinline__ ushort f2bfu(float f) {
    __hip_bfloat16 h = __float2bfloat16(f);
    return *(ushort*)&h;
}
__device__ __forceinline__ float bfu2f(ushort u) {
    union { unsigned int i; float f; } x; x.i = ((unsigned int)u) << 16; return x.f;
}

// ---------------- fp32 -> bf16 elementwise convert ----------------
__global__ __launch_bounds__(256) void cvt_bf16(const float* __restrict__ src,
                                                ushort* __restrict__ dst, int n) {
    int i = (blockIdx.x * 256 + threadIdx.x) * 8;
    if (i >= n) return;
    float4 a = *(const float4*)(src + i);
    float4 b = *(const float4*)(src + i + 4);
    ushort4 ua = {f2bfu(a.x), f2bfu(a.y), f2bfu(a.z), f2bfu(a.w)};
    ushort4 ub = {f2bfu(b.x), f2bfu(b.y), f2bfu(b.z), f2bfu(b.w)};
    *(ushort4*)(dst + i) = ua;
    *(ushort4*)(dst + i + 4) = ub;
}

// ---------------- fp32 [R,C] -> bf16 [C,R] transpose+convert (64x64 tiles) ----------------
__global__ __launch_bounds__(256) void transpose_cvt(const float* __restrict__ src,
                                                     ushort* __restrict__ dst,
                                                     int R, int C) {
    __shared__ ushort tile[64][68];
    int t = threadIdx.x;
    int tr = blockIdx.y * 64, tc = blockIdx.x * 64;
    int r0 = t >> 4;
    int c4 = (t & 15) << 2;
#pragma unroll
    for (int p = 0; p < 4; ++p) {
        int row = r0 + p * 16;
        float4 v = *(const float4*)&src[(size_t)(tr + row) * C + tc + c4];
        tile[row][c4 + 0] = f2bfu(v.x);
        tile[row][c4 + 1] = f2bfu(v.y);
        tile[row][c4 + 2] = f2bfu(v.z);
        tile[row][c4 + 3] = f2bfu(v.w);
    }
    __syncthreads();
#pragma unroll
    for (int p = 0; p < 4; ++p) {
        int orow = r0 + p * 16;
        ushort4 u;
        u.x = tile[c4 + 0][orow];
        u.y = tile[c4 + 1][orow];
        u.z = tile[c4 + 2][orow];
        u.w = tile[c4 + 3][orow];
        *(ushort4*)&dst[(size_t)(tc + orow) * R + tr + c4] = u;
    }
}

// ---------------- bf16 MFMA GEMM: C[M,N] = A[M,K] * Bt[N,K]^T ----------------
// EPI: 0 = bf16 store, 1 = sigmoid bf16 store, 2 = fp32 store
template <int EPI>
__global__ __launch_bounds__(256) void gemm_bt(const ushort* __restrict__ A,
                                               const ushort* __restrict__ Bt,
                                               void* __restrict__ Cout,
                                               int M, int N, int K) {
    __shared__ ushort As[128 * 40];
    __shared__ ushort Bs[128 * 40];
    int tid = threadIdx.x;
    int lane = tid & 63, wave = tid >> 6;
    int lane15 = lane & 15, quad = lane >> 4;
    int bm = blockIdx.y * 128, bn = blockIdx.x * 128;
    int wr = (wave & 1) * 64, wc = (wave >> 1) * 64;
    f32x4 acc[4][4] = {};
    for (int k0 = 0; k0 < K; k0 += 32) {
#pragma unroll
        for (int p = 0; p < 2; ++p) {
            int c = p * 256 + tid;
            int row = c >> 2, col8 = (c & 3) << 3;
            *(uint4*)&As[row * 40 + col8] = *(const uint4*)&A[(size_t)(bm + row) * K + k0 + col8];
            *(uint4*)&Bs[row * 40 + col8] = *(const uint4*)&Bt[(size_t)(bn + row) * K + k0 + col8];
        }
        __syncthreads();
        bf16x8 af[4], bfr[4];
#pragma unroll
        for (int i = 0; i < 4; ++i)
            af[i] = *(const bf16x8*)&As[(wr + i * 16 + lane15) * 40 + quad * 8];
#pragma unroll
        for (int j = 0; j < 4; ++j)
            bfr[j] = *(const bf16x8*)&Bs[(wc + j * 16 + lane15) * 40 + quad * 8];
#pragma unroll
        for (int i = 0; i < 4; ++i)
#pragma unroll
            for (int j = 0; j < 4; ++j)
                acc[i][j] = __builtin_amdgcn_mfma_f32_16x16x32_bf16(af[i], bfr[j], acc[i][j], 0, 0, 0);
        __syncthreads();
    }
#pragma unroll
    for (int i = 0; i < 4; ++i) {
#pragma unroll
        for (int j = 0; j < 4; ++j) {
            int rbase = bm + wr + i * 16 + quad * 4;
            int col = bn + wc + j * 16 + lane15;
#pragma unroll
            for (int r = 0; r < 4; ++r) {
                float v = acc[i][j][r];
                size_t idx = (size_t)(rbase + r) * N + col;
                if (EPI == 0)      ((ushort*)Cout)[idx] = f2bfu(v);
                else if (EPI == 1) ((ushort*)Cout)[idx] = f2bfu(1.0f / (1.0f + expf(-v)));
                else               ((float*)Cout)[idx] = v;
            }
        }
    }
}

// ---------------- q/k RMSNorm + RoPE + q scale (in-place on bf16 qkv) ----------------
__global__ __launch_bounds__(64) void qk_post(ushort* __restrict__ qkv,
                                              const int* __restrict__ positions,
                                              const float* __restrict__ qw,
                                              const float* __restrict__ kw) {
    int th = blockIdx.x;
    int t = th >> 4, h = th & 15;
    int lane = threadIdx.x;
    ushort* qp = qkv + (size_t)t * QKV_N + h * 128;
    ushort* kp = qp + 2048;
    float q0 = bfu2f(qp[lane]), q1 = bfu2f(qp[lane + 64]);
    float k0 = bfu2f(kp[lane]), k1 = bfu2f(kp[lane + 64]);
    float sq = q0 * q0 + q1 * q1;
    float sk = k0 * k0 + k1 * k1;
#pragma unroll
    for (int off = 32; off > 0; off >>= 1) {
        sq += __shfl_xor(sq, off);
        sk += __shfl_xor(sk, off);
    }
    float rq = rsqrtf(sq * (1.0f / 128.0f) + 1e-6f);
    float rk = rsqrtf(sk * (1.0f / 128.0f) + 1e-6f);
    q0 *= rq * qw[lane]; q1 *= rq * qw[lane + 64];
    k0 *= rk * kw[lane]; k1 *= rk * kw[lane + 64];
    int pos = positions[t];
    int fi = lane & 31;
    float inv_freq = powf(10000.0f, -(float)fi * (1.0f / 32.0f));
    float freq = (float)pos * inv_freq;
    float sn = sinf(freq), cs = cosf(freq);
    float qo = __shfl_xor(q0, 32);
    float ko = __shfl_xor(k0, 32);
    float qr, kr;
    if (lane < 32) { qr = q0 * cs - qo * sn; kr = k0 * cs - ko * sn; }
    else           { qr = q0 * cs + qo * sn; kr = k0 * cs + ko * sn; }
    const float scale = 0.08838834764831845f;  // 128^-0.5
    qp[lane]      = f2bfu(qr * scale);
    qp[lane + 64] = f2bfu(q1 * scale);
    kp[lane]      = f2bfu(kr);
    kp[lane + 64] = f2bfu(k1);
}

// ---------------- per-chunk partial state: P[c,h] = sum_j lam^{127-j} k_j v_j^T ----------------
__global__ __launch_bounds__(256) void chunk_partial(const ushort* __restrict__ qkv,
                                                     float* __restrict__ P) {
    int c = blockIdx.x, h = blockIdx.y;
    float slope = head_slope(h);
    __shared__ float Ks[16][132];
    __shared__ float Vs[16][132];
    int tid = threadIdx.x, ty = tid >> 4, tx = tid & 15;
    float acc[8][8] = {};
    int t0 = c * CHUNK;
    for (int j0 = 0; j0 < CHUNK; j0 += 16) {
        __syncthreads();
        {
            int row = tid >> 4, c8 = (tid & 15) << 3;
            const ushort* base = qkv + (size_t)(t0 + j0 + row) * QKV_N + h * 128 + c8;
            bf16x8 kv = *(const bf16x8*)(base + 2048);
            bf16x8 vv = *(const bf16x8*)(base + 4096);
            float w = expf(slope * (float)(127 - (j0 + row)));
#pragma unroll
            for (int i = 0; i < 8; ++i) {
                Ks[row][c8 + i] = (float)kv[i] * w;
                Vs[row][c8 + i] = (float)vv[i];
            }
        }
        __syncthreads();
        for (int jj = 0; jj < 16; ++jj) {
            float kr[8], vr[8];
#pragma unroll
            for (int a = 0; a < 8; ++a) kr[a] = Ks[jj][ty * 8 + a];
#pragma unroll
            for (int b = 0; b < 8; ++b) vr[b] = Vs[jj][tx + 16 * b];
#pragma unroll
            for (int a = 0; a < 8; ++a)
#pragma unroll
                for (int b = 0; b < 8; ++b)
                    acc[a][b] += kr[a] * vr[b];
        }
    }
    float* Pb = P + (size_t)(c * 16 + h) * 16384;
#pragma unroll
    for (int a = 0; a < 8; ++a)
#pragma unroll
        for (int b = 0; b < 8; ++b)
            Pb[(ty * 8 + a) * 128 + tx + 16 * b] = acc[a][b];
}

// ---------------- sequential scan over 32 chunks, in place (P -> S_prefix) ----------------
__global__ __launch_bounds__(128) void scan_states(float* __restrict__ PS,
                                                   const float* __restrict__ S0,
                                                   float* __restrict__ Sfin) {
    int hk = blockIdx.x;          // h*128 + krow
    int v = threadIdx.x;
    int h = hk >> 7;
    float lamC = expf(head_slope(h) * 128.0f);
    size_t off = (size_t)hk * 128 + v;
    float s = S0[off];
#pragma unroll
    for (int c = 0; c < 32; ++c) {
        size_t idx = (size_t)c * 262144 + off;
        float p = PS[idx];
        PS[idx] = s;               // state BEFORE chunk c
        s = s * lamC + p;
    }
    Sfin[off] = s;
}

// ---------------- per-chunk output: intra attention + inter via S_prefix ----------------
__global__ __launch_bounds__(256) void chunk_out(const ushort* __restrict__ qkv,
                                                 const float* __restrict__ Sp,
                                                 float* __restrict__ o) {
    int c = blockIdx.x, half = blockIdx.y, h = blockIdx.z;
    float slope = head_slope(h);
    __shared__ float Qs[64][20];
    __shared__ float Ks[128][17];
    __shared__ float SVs[16][132];
    __shared__ float ScL[64][132];
    int tid = threadIdx.x, ty = tid >> 4, tx = tid & 15;
    int t0 = c * CHUNK;
    int th0 = t0 + half * 64;
    float acc1[4][8] = {};   // scores (pre-mask)
    float acc3[4][8] = {};   // q . S_prev
    for (int d0 = 0; d0 < 128; d0 += 16) {
        __syncthreads();
        {   // Q tile: 64 rows x 16 cols
            int row = tid >> 2, c4 = (tid & 3) << 2;
            const ushort* src = qkv + (size_t)(th0 + row) * QKV_N + h * 128 + d0 + c4;
            bf16x4 qv = *(const bf16x4*)src;
#pragma unroll
            for (int i = 0; i < 4; ++i) Qs[row][c4 + i] = (float)qv[i];
        }
        {   // K tile: 128 rows x 16 cols
            int row = tid >> 1, c8 = (tid & 1) << 3;
            const ushort* src = qkv + (size_t)(t0 + row) * QKV_N + 2048 + h * 128 + d0 + c8;
            bf16x8 kv = *(const bf16x8*)src;
#pragma unroll
            for (int i = 0; i < 8; ++i) Ks[row][c8 + i] = (float)kv[i];
        }
#pragma unroll
        for (int p = 0; p < 2; ++p) {   // S_prev slice: 16 rows x 128 cols (fp32)
            int idx = p * 256 + tid;
            int row = idx >> 5, c4 = (idx & 31) << 2;
            const float* src = Sp + (size_t)(c * 16 + h) * 16384 + (size_t)(d0 + row) * 128 + c4;
            *(float4*)&SVs[row][c4] = *(const float4*)src;
        }
        __syncthreads();
        for (int dd = 0; dd < 16; ++dd) {
            float qr[4], kr[8], sr[8];
#pragma unroll
            for (int a = 0; a < 4; ++a) qr[a] = Qs[ty * 4 + a][dd];
#pragma unroll
            for (int b = 0; b < 8; ++b) kr[b] = Ks[tx + 16 * b][dd];
#pragma unroll
            for (int b = 0; b < 8; ++b) sr[b] = SVs[dd][tx + 16 * b];
#pragma unroll
            for (int a = 0; a < 4; ++a)
#pragma unroll
                for (int b = 0; b < 8; ++b) {
                    acc1[a][b] += qr[a] * kr[b];
                    acc3[a][b] += qr[a] * sr[b];
                }
        }
    }
    // mask + decay the scores, park them in LDS
#pragma unroll
    for (int a = 0; a < 4; ++a) {
        int tl = half * 64 + ty * 4 + a;
#pragma unroll
        for (int b = 0; b < 8; ++b) {
            int s = tx + 16 * b;
            float v = (s <= tl) ? acc1[a][b] * expf(slope * (float)(tl - s)) : 0.0f;
            ScL[ty * 4 + a][s] = v;
        }
    }
    __syncthreads();
    float acc2[4][8] = {};
    for (int s0 = 0; s0 < 128; s0 += 16) {
        __syncthreads();
        {   // V tile: 16 rows x 128 cols
            int row = tid >> 4, c8 = (tid & 15) << 3;
            const ushort* src = qkv + (size_t)(t0 + s0 + row) * QKV_N + 4096 + h * 128 + c8;
            bf16x8 vv = *(const bf16x8*)src;
#pragma unroll
            for (int i = 0; i < 8; ++i) SVs[row][c8 + i] = (float)vv[i];
        }
        __syncthreads();
        for (int jj = 0; jj < 16; ++jj) {
            float sc[4], vr[8];
#pragma unroll
            for (int a = 0; a < 4; ++a) sc[a] = ScL[ty * 4 + a][s0 + jj];
#pragma unroll
            for (int b = 0; b < 8; ++b) vr[b] = SVs[jj][tx + 16 * b];
#pragma unroll
            for (int a = 0; a < 4; ++a)
#pragma unroll
                for (int b = 0; b < 8; ++b)
                    acc2[a][b] += sc[a] * vr[b];
        }
    }
#pragma unroll
    for (int a = 0; a < 4; ++a) {
        int tl = half * 64 + ty * 4 + a;
        float inter = expf(slope * (float)(tl + 1));
#pragma unroll
        for (int b = 0; b < 8; ++b)
            o[(size_t)(t0 + tl) * 2048 + h * 128 + tx + 16 * b] = acc2[a][b] + inter * acc3[a][b];
    }
}

// ---------------- group RMS-norm * g_norm_w * sigmoid-gate -> bf16 ----------------
__global__ __launch_bounds__(256) void gnorm_gate(const float* __restrict__ o,
                                                  const ushort* __restrict__ gate,
                                                  const float* __restrict__ gw,
                                                  ushort* __restrict__ gg) {
    int t = blockIdx.x;
    int tid = threadIdx.x;
    const float* op = o + (size_t)t * 2048;
    float4 xa = *(const float4*)(op + tid * 8);
    float4 xb = *(const float4*)(op + tid * 8 + 4);
    float x[8] = {xa.x, xa.y, xa.z, xa.w, xb.x, xb.y, xb.z, xb.w};
    float ss = 0.0f;
#pragma unroll
    for (int i = 0; i < 8; ++i) ss += x[i] * x[i];
#pragma unroll
    for (int off = 16; off > 0; off >>= 1) ss += __shfl_xor(ss, off);  // reduce over 32-thread group
    float r = rsqrtf(ss * (1.0f / 256.0f) + 1e-6f);
    const ushort* gp = gate + (size_t)t * 2048;
#pragma unroll
    for (int i = 0; i < 8; ++i) {
        int j = tid * 8 + i;
        float val = x[i] * r * gw[j] * bfu2f(gp[j]);
        gg[(size_t)t * 2048 + j] = f2bfu(val);
    }
}

extern "C" void kernel_launch(void* const* d_in, const int* in_sizes, int n_in,
                              void* d_out, int out_size, void* d_ws, size_t ws_size,
                              hipStream_t stream) {
    const int* positions   = (const int*)d_in[0];
    const float* hidden    = (const float*)d_in[1];   // fp32 T x 2048
    const float* S0        = (const float*)d_in[2];   // fp32 16x128x128
    const float* w_qkv     = (const float*)d_in[3];   // fp32 2048 x 6144
    const float* w_g       = (const float*)d_in[4];   // fp32 2048 x 2048
    const float* w_dense   = (const float*)d_in[5];   // fp32 2048 x 2048
    const float* qw        = (const float*)d_in[6];
    const float* kw        = (const float*)d_in[7];
    const float* gw        = (const float*)d_in[8];

    char* ws = (char*)d_ws;
    ushort* qkv     = (ushort*)ws;                    // bf16 T x 6144          [0, 50331648)
    float*  PS      = (float*)(ws + 50331648);        // fp32 32x16x128x128     [50331648, 83886080)
    ushort* gatebuf = (ushort*)(ws + 83886080);       // bf16 T x 2048          [83886080, 100663296)
    ushort* hid_b   = (ushort*)(ws + 100663296);      // bf16 T x 2048          [100663296, 117440512)
    ushort* wqkv_t  = (ushort*)(ws + 117440512);      // bf16 6144 x 2048       [117440512, 142606336)
    ushort* wg_t    = (ushort*)(ws + 142606336);      // bf16 2048 x 2048       [142606336, 150994944)
    ushort* wd_t    = (ushort*)(ws + 150994944);      // bf16 2048 x 2048       [150994944, 159383552)
    ushort* gg      = (ushort*)ws;                    // aliases qkv (dead by then)

    float* out  = (float*)d_out;
    float* Sfin = out + (size_t)T_SEQ * HID_C;        // 16x128x128 fp32
    float* obuf = out;                                // out-region doubles as attn scratch

    cvt_bf16<<<T_SEQ * HID_C / (256 * 8), 256, 0, stream>>>(hidden, hid_b, T_SEQ * HID_C);
    transpose_cvt<<<dim3(QKV_N / 64, HID_C / 64), 256, 0, stream>>>(w_qkv, wqkv_t, HID_C, QKV_N);
    transpose_cvt<<<dim3(HID_C / 64, HID_C / 64), 256, 0, stream>>>(w_g, wg_t, HID_C, HID_C);
    transpose_cvt<<<dim3(HID_C / 64, HID_C / 64), 256, 0, stream>>>(w_dense, wd_t, HID_C, HID_C);

    gemm_bt<0><<<dim3(QKV_N / 128, T_SEQ / 128), 256, 0, stream>>>(hid_b, wqkv_t, qkv, T_SEQ, QKV_N, HID_C);
    gemm_bt<1><<<dim3(HID_C / 128, T_SEQ / 128), 256, 0, stream>>>(hid_b, wg_t, gatebuf, T_SEQ, HID_C, HID_C);

    qk_post<<<T_SEQ * NH, 64, 0, stream>>>(qkv, positions, qw, kw);
    chunk_partial<<<dim3(32, 16), 256, 0, stream>>>(qkv, PS);
    scan_states<<<2048, 128, 0, stream>>>(PS, S0, Sfin);
    chunk_out<<<dim3(32, 2, 16), 256, 0, stream>>>(qkv, PS, obuf);
    gnorm_gate<<<T_SEQ, 256, 0, stream>>>(obuf, gatebuf, gw, gg);

    gemm_bt<2><<<dim3(HID_C / 128, T_SEQ / 128), 256, 0, stream>>>(gg, wd_t, out, T_SEQ, HID_C, HID_C);
}

// Round 3
// 504.612 us; speedup vs baseline: 1.2002x; 1.2002x over previous
//
#include <hip/hip_runtime.h>
#include <hip/hip_bf16.h>

using bf16x8 = __attribute__((ext_vector_type(8))) __bf16;
using f32x4  = __attribute__((ext_vector_type(4))) float;

constexpr int T_SEQ = 4096;
constexpr int HID_C = 2048;
constexpr int NH    = 16;
constexpr int QKV_N = 6144;

__device__ __forceinline__ float head_slope(int h) {
    // slope[h] = -2^{-(h+1)/2} * (1 - 1/31 + 1e-5)
    return -exp2f(-0.5f * (float)(h + 1)) * 0.967751935483871f;
}

__device__ __forceinline__ ushort f2bfu(float f) {
    __hip_bfloat16 h = __float2bfloat16(f);
    return *(ushort*)&h;
}
__device__ __forceinline__ float bfu2f(ushort u) {
    union { unsigned int i; float f; } x; x.i = ((unsigned int)u) << 16; return x.f;
}

// async global -> LDS, 16 bytes per lane; LDS dest = wave-uniform base + lane*16
__device__ __forceinline__ void async16(const ushort* g, ushort* l) {
    __builtin_amdgcn_global_load_lds((const __attribute__((address_space(1))) void*)g,
                                     (__attribute__((address_space(3))) void*)l, 16, 0, 0);
}

// ---------------- fp32 -> bf16 elementwise convert ----------------
__global__ __launch_bounds__(256) void cvt_bf16(const float* __restrict__ src,
                                                ushort* __restrict__ dst, int n) {
    int i = (blockIdx.x * 256 + threadIdx.x) * 8;
    if (i >= n) return;
    float4 a = *(const float4*)(src + i);
    float4 b = *(const float4*)(src + i + 4);
    ushort4 ua = {f2bfu(a.x), f2bfu(a.y), f2bfu(a.z), f2bfu(a.w)};
    ushort4 ub = {f2bfu(b.x), f2bfu(b.y), f2bfu(b.z), f2bfu(b.w)};
    *(ushort4*)(dst + i) = ua;
    *(ushort4*)(dst + i + 4) = ub;
}

// ---------------- fp32 [R,C] -> bf16 [C,R] transpose+convert (64x64 tiles) ----------------
__global__ __launch_bounds__(256) void transpose_cvt(const float* __restrict__ src,
                                                     ushort* __restrict__ dst,
                                                     int R, int C) {
    __shared__ ushort tile[64][68];
    int t = threadIdx.x;
    int tr = blockIdx.y * 64, tc = blockIdx.x * 64;
    int r0 = t >> 4;
    int c4 = (t & 15) << 2;
#pragma unroll
    for (int p = 0; p < 4; ++p) {
        int row = r0 + p * 16;
        float4 v = *(const float4*)&src[(size_t)(tr + row) * C + tc + c4];
        tile[row][c4 + 0] = f2bfu(v.x);
        tile[row][c4 + 1] = f2bfu(v.y);
        tile[row][c4 + 2] = f2bfu(v.z);
        tile[row][c4 + 3] = f2bfu(v.w);
    }
    __syncthreads();
#pragma unroll
    for (int p = 0; p < 4; ++p) {
        int orow = r0 + p * 16;
        ushort4 u;
        u.x = tile[c4 + 0][orow];
        u.y = tile[c4 + 1][orow];
        u.z = tile[c4 + 2][orow];
        u.w = tile[c4 + 3][orow];
        *(ushort4*)&dst[(size_t)(tc + orow) * R + tr + c4] = u;
    }
}

// ------- per-head transpose of k and v: [T][128] slice of qkv -> [128][T] -------
__global__ __launch_bounds__(256) void transpose_kv(const ushort* __restrict__ qkv,
                                                    ushort* __restrict__ kT,
                                                    ushort* __restrict__ vT) {
    __shared__ ushort tile[64][72];
    int bt = blockIdx.x;             // t-tile (64 wide)
    int bd = blockIdx.y;             // d-tile (2)
    int hz = blockIdx.z;             // h*2 + isv
    int h = hz >> 1, isv = hz & 1;
    const ushort* src = qkv + 2048 + isv * 2048 + h * 128 + bd * 64;
    ushort* dst = (isv ? vT : kT) + (size_t)(h * 128 + bd * 64) * T_SEQ + bt * 64;
    int tid = threadIdx.x;
    int r0 = tid >> 4, c4 = (tid & 15) << 2;
#pragma unroll
    for (int p = 0; p < 4; ++p) {
        int row = r0 + p * 16;
        *(ushort4*)&tile[row][c4] = *(const ushort4*)&src[(size_t)(bt * 64 + row) * QKV_N + c4];
    }
    __syncthreads();
#pragma unroll
    for (int p = 0; p < 4; ++p) {
        int orow = r0 + p * 16;      // local d index
        ushort4 u;
        u.x = tile[c4 + 0][orow];
        u.y = tile[c4 + 1][orow];
        u.z = tile[c4 + 2][orow];
        u.w = tile[c4 + 3][orow];
        *(ushort4*)&dst[(size_t)orow * T_SEQ + c4] = u;
    }
}

// ---------------- bf16 MFMA GEMM (m97-style DMA staging + swizzle) ----------------
// C[M,N] = A[M,K] * Bt[N,K]^T.  EPI: 0 = bf16 store, 1 = sigmoid bf16, 2 = fp32
template <int EPI>
__global__ __launch_bounds__(256) void gemm_bt(const ushort* __restrict__ A,
                                               const ushort* __restrict__ Bt,
                                               void* __restrict__ Cout,
                                               int M, int N, int K) {
    __shared__ ushort As[128 * 32];
    __shared__ ushort Bs[128 * 32];
    int tid = threadIdx.x;
    int lane = tid & 63, wave = tid >> 6;
    int lane15 = lane & 15, quad = lane >> 4;
    int bm = blockIdx.y * 128, bn = blockIdx.x * 128;
    int wr = (wave & 1) * 64, wc = (wave >> 1) * 64;
    // staging: wave w DMAs chunks 2w,2w+1 (16 rows x 32 cols each) of A and B.
    // swizzle: global col-group cg = (lane&3) ^ ((lane>>3)&3); LDS slot = lane&3.
    int ch0 = wave * 2;
    int lrow = lane >> 2;
    int cg = (lane & 3) ^ ((lane >> 3) & 3);
    const ushort* gA0 = A + (size_t)(bm + ch0 * 16 + lrow) * K + cg * 8;
    const ushort* gA1 = gA0 + (size_t)16 * K;
    const ushort* gB0 = Bt + (size_t)(bn + ch0 * 16 + lrow) * K + cg * 8;
    const ushort* gB1 = gB0 + (size_t)16 * K;
    ushort* lA0 = As + ch0 * 512;
    ushort* lA1 = lA0 + 512;
    ushort* lB0 = Bs + ch0 * 512;
    ushort* lB1 = lB0 + 512;
    f32x4 acc[4][4] = {};
    for (int k0 = 0; k0 < K; k0 += 32) {
        async16(gA0 + k0, lA0);
        async16(gA1 + k0, lA1);
        async16(gB0 + k0, lB0);
        async16(gB1 + k0, lB1);
        __syncthreads();
        bf16x8 af[4], bfr[4];
#pragma unroll
        for (int i = 0; i < 4; ++i) {
            int row = wr + i * 16 + lane15;
            af[i] = *(const bf16x8*)&As[row * 32 + ((quad ^ ((row >> 1) & 3)) * 8)];
        }
#pragma unroll
        for (int j = 0; j < 4; ++j) {
            int row = wc + j * 16 + lane15;
            bfr[j] = *(const bf16x8*)&Bs[row * 32 + ((quad ^ ((row >> 1) & 3)) * 8)];
        }
#pragma unroll
        for (int i = 0; i < 4; ++i)
#pragma unroll
            for (int j = 0; j < 4; ++j)
                acc[i][j] = __builtin_amdgcn_mfma_f32_16x16x32_bf16(af[i], bfr[j], acc[i][j], 0, 0, 0);
        __syncthreads();
    }
#pragma unroll
    for (int i = 0; i < 4; ++i) {
#pragma unroll
        for (int j = 0; j < 4; ++j) {
            int rbase = bm + wr + i * 16 + quad * 4;
            int col = bn + wc + j * 16 + lane15;
#pragma unroll
            for (int r = 0; r < 4; ++r) {
                float v = acc[i][j][r];
                size_t idx = (size_t)(rbase + r) * N + col;
                if (EPI == 0)      ((ushort*)Cout)[idx] = f2bfu(v);
                else if (EPI == 1) ((ushort*)Cout)[idx] = f2bfu(1.0f / (1.0f + __expf(-v)));
                else               ((float*)Cout)[idx] = v;
            }
        }
    }
}

// ---------------- q/k RMSNorm + RoPE + q scale (in-place on bf16 qkv) ----------------
__global__ __launch_bounds__(256) void qk_post(ushort* __restrict__ qkv,
                                               const int* __restrict__ positions,
                                               const float* __restrict__ qw,
                                               const float* __restrict__ kw) {
    int t = blockIdx.x;
    int tid = threadIdx.x;
    int h = tid >> 4;
    int grp = tid & 15;
    int d8 = grp * 8;
    ushort* qp = qkv + (size_t)t * QKV_N + h * 128 + d8;
    ushort* kp = qp + 2048;
    bf16x8 qv = *(const bf16x8*)qp;
    bf16x8 kv = *(const bf16x8*)kp;
    float q[8], k[8];
    float sq = 0.f, sk = 0.f;
#pragma unroll
    for (int i = 0; i < 8; ++i) {
        q[i] = (float)qv[i]; k[i] = (float)kv[i];
        sq += q[i] * q[i];   sk += k[i] * k[i];
    }
#pragma unroll
    for (int off = 1; off < 16; off <<= 1) {
        sq += __shfl_xor(sq, off);
        sk += __shfl_xor(sk, off);
    }
    float rq = rsqrtf(sq * (1.0f / 128.0f) + 1e-6f);
    float rk = rsqrtf(sk * (1.0f / 128.0f) + 1e-6f);
#pragma unroll
    for (int i = 0; i < 8; ++i) {
        q[i] *= rq * qw[d8 + i];
        k[i] *= rk * kw[d8 + i];
    }
    // rope partner (d ^ 32  <->  lane ^ 4)
    float qo[8], ko[8];
#pragma unroll
    for (int i = 0; i < 8; ++i) { qo[i] = __shfl_xor(q[i], 4); ko[i] = __shfl_xor(k[i], 4); }
    if (grp < 8) {
        float pos = (float)positions[t];
        bool lo = grp < 4;
#pragma unroll
        for (int i = 0; i < 8; ++i) {
            int fi = (d8 + i) & 31;
            float freq = pos * __expf((float)fi * -0.2878231366f);  // 10000^(-fi/32)
            float sn, cs;
            __sincosf(freq, &sn, &cs);
            if (lo) { q[i] = q[i] * cs - qo[i] * sn; k[i] = k[i] * cs - ko[i] * sn; }
            else    { q[i] = q[i] * cs + qo[i] * sn; k[i] = k[i] * cs + ko[i] * sn; }
        }
    }
    const float scale = 0.08838834764831845f;  // 128^-0.5
    bf16x8 qs, ks;
#pragma unroll
    for (int i = 0; i < 8; ++i) { qs[i] = (__bf16)(q[i] * scale); ks[i] = (__bf16)k[i]; }
    *(bf16x8*)qp = qs;
    *(bf16x8*)kp = ks;
}

// ------- per-chunk partial state (transposed): PT[c,h][v][d] = sum_j lam^(127-j) v_j[v] k_j[d] -------
__global__ __launch_bounds__(256) void chunk_partial(const ushort* __restrict__ kT,
                                                     const ushort* __restrict__ vT,
                                                     float* __restrict__ PT) {
    int c = blockIdx.x, h = blockIdx.y;
    float slope = head_slope(h);
    float lam_inv = __expf(-slope);
    int tid = threadIdx.x, lane = tid & 63, wave = tid >> 6;
    int lane15 = lane & 15, quad = lane >> 4;
    int wv = (wave & 1) * 64, wd = (wave >> 1) * 64;
    const ushort* vbase = vT + (size_t)h * 128 * T_SEQ + c * 128;
    const ushort* kbase = kT + (size_t)h * 128 * T_SEQ + c * 128;
    f32x4 acc[4][4] = {};
#pragma unroll
    for (int j0 = 0; j0 < 128; j0 += 32) {
        float w8[8];
        w8[0] = __expf(slope * (float)(127 - (j0 + quad * 8)));
#pragma unroll
        for (int kk = 1; kk < 8; ++kk) w8[kk] = w8[kk - 1] * lam_inv;
        bf16x8 afr[4], bfr[4];
#pragma unroll
        for (int i = 0; i < 4; ++i) {
            bf16x8 v = *(const bf16x8*)&vbase[(size_t)(wv + i * 16 + lane15) * T_SEQ + j0 + quad * 8];
#pragma unroll
            for (int kk = 0; kk < 8; ++kk) afr[i][kk] = (__bf16)((float)v[kk] * w8[kk]);
        }
#pragma unroll
        for (int j = 0; j < 4; ++j)
            bfr[j] = *(const bf16x8*)&kbase[(size_t)(wd + j * 16 + lane15) * T_SEQ + j0 + quad * 8];
#pragma unroll
        for (int i = 0; i < 4; ++i)
#pragma unroll
            for (int j = 0; j < 4; ++j)
                acc[i][j] = __builtin_amdgcn_mfma_f32_16x16x32_bf16(afr[i], bfr[j], acc[i][j], 0, 0, 0);
    }
    float* out = PT + ((size_t)c * 16 + h) * 16384;
#pragma unroll
    for (int i = 0; i < 4; ++i)
#pragma unroll
        for (int j = 0; j < 4; ++j)
#pragma unroll
            for (int r = 0; r < 4; ++r)
                out[(size_t)(wv + i * 16 + quad * 4 + r) * 128 + wd + j * 16 + lane15] = acc[i][j][r];
}

// ------- sequential scan over 32 chunks: PT -> Spb (bf16 prefix states) + Sfin -------
__global__ __launch_bounds__(128) void scan_states(const float* __restrict__ PT,
                                                   const float* __restrict__ S0,
                                                   ushort* __restrict__ Spb,
                                                   float* __restrict__ Sfin) {
    int hv = blockIdx.x;              // h*128 + v
    int d = threadIdx.x;              // k-dim
    int h = hv >> 7, v = hv & 127;
    float lamC = __expf(head_slope(h) * 128.0f);
    float s = S0[(size_t)h * 16384 + d * 128 + v];
#pragma unroll
    for (int c = 0; c < 32; ++c) {
        size_t idx = ((size_t)c * 2048 + hv) * 128 + d;
        Spb[idx] = f2bfu(s);          // state BEFORE chunk c, layout [c][h][v][d]
        s = s * lamC + PT[idx];
    }
    Sfin[(size_t)h * 16384 + d * 128 + v] = s;
}

// ------- per-chunk output: QK^T (masked/decayed) * V + lam^(t+1) * Q * S_prev -------
__global__ __launch_bounds__(256) void chunk_out(const ushort* __restrict__ qkv,
                                                 const ushort* __restrict__ vT,
                                                 const ushort* __restrict__ Spb,
                                                 float* __restrict__ o) {
    int c = blockIdx.x, h = blockIdx.y;
    float slope = head_slope(h);
    __shared__ ushort Ps[128 * 136];   // padded: row stride 272B -> conflict-free b128
    int tid = threadIdx.x, lane = tid & 63, wave = tid >> 6;
    int lane15 = lane & 15, quad = lane >> 4;
    int t0 = c * 128;
    int tt0 = wave, tt1 = 7 - wave;    // owned t-tiles (balanced triangular split)
    const ushort* qbase = qkv + (size_t)t0 * QKV_N + h * 128;
    const ushort* kbase = qbase + 2048;

    bf16x8 qf0[4], qf1[4];
#pragma unroll
    for (int ds = 0; ds < 4; ++ds) {
        qf0[ds] = *(const bf16x8*)&qbase[(size_t)(tt0 * 16 + lane15) * QKV_N + ds * 32 + quad * 8];
        qf1[ds] = *(const bf16x8*)&qbase[(size_t)(tt1 * 16 + lane15) * QKV_N + ds * 32 + quad * 8];
    }
    // ---- phase 1: scores ----
    f32x4 s0a[4] = {};
    f32x4 s1a[8] = {};
#pragma unroll
    for (int st = 0; st < 8; ++st) {
        if (st <= tt1) {
            bf16x8 kf[4];
#pragma unroll
            for (int ds = 0; ds < 4; ++ds)
                kf[ds] = *(const bf16x8*)&kbase[(size_t)(st * 16 + lane15) * QKV_N + ds * 32 + quad * 8];
#pragma unroll
            for (int ds = 0; ds < 4; ++ds)
                s1a[st] = __builtin_amdgcn_mfma_f32_16x16x32_bf16(qf1[ds], kf[ds], s1a[st], 0, 0, 0);
            if (st <= tt0) {
#pragma unroll
                for (int ds = 0; ds < 4; ++ds)
                    s0a[st] = __builtin_amdgcn_mfma_f32_16x16x32_bf16(qf0[ds], kf[ds], s0a[st], 0, 0, 0);
            }
        }
    }
    // ---- park masked/decayed scores (zero strip pads odd 16-blocks to 32) ----
    int stmax0 = tt0 + ((tt0 & 1) ? 0 : 1);
    int stmax1 = tt1 + ((tt1 & 1) ? 0 : 1);
#pragma unroll
    for (int st = 0; st < 8; ++st) {
        if (st <= stmax1) {
#pragma unroll
            for (int r = 0; r < 4; ++r) {
                int t = tt1 * 16 + quad * 4 + r;
                int s = st * 16 + lane15;
                float val = 0.f;
                if (st <= tt1) val = (s <= t) ? s1a[st][r] * __expf(slope * (float)(t - s)) : 0.f;
                Ps[t * 136 + s] = f2bfu(val);
            }
        }
    }
#pragma unroll
    for (int st = 0; st < 5; ++st) {
        if (st <= stmax0) {
#pragma unroll
            for (int r = 0; r < 4; ++r) {
                int t = tt0 * 16 + quad * 4 + r;
                int s = st * 16 + lane15;
                float val = 0.f;
                if (st <= tt0) val = (s <= t) ? s0a[st][r] * __expf(slope * (float)(t - s)) : 0.f;
                Ps[t * 136 + s] = f2bfu(val);
            }
        }
    }
    __syncthreads();
    // ---- phase 2: O = P*V + diag(lam^(t+1)) Q*S_prev ----
    f32x4 oa0[8] = {};
    f32x4 oa1[8] = {};
    // inter-chunk: scaled-Q fragments (scale uniform per lane: m = lane15 = t)
    float lam0 = __expf(slope * (float)(tt0 * 16 + lane15 + 1));
    float lam1 = __expf(slope * (float)(tt1 * 16 + lane15 + 1));
    bf16x8 qs0[4], qs1[4];
#pragma unroll
    for (int ds = 0; ds < 4; ++ds)
#pragma unroll
        for (int kk = 0; kk < 8; ++kk) {
            qs0[ds][kk] = (__bf16)((float)qf0[ds][kk] * lam0);
            qs1[ds][kk] = (__bf16)((float)qf1[ds][kk] * lam1);
        }
    const ushort* spb = Spb + ((size_t)c * 2048 + h * 128) * 128;
#pragma unroll
    for (int vt = 0; vt < 8; ++vt)
#pragma unroll
        for (int ds = 0; ds < 4; ++ds) {
            bf16x8 bfrag = *(const bf16x8*)&spb[(vt * 16 + lane15) * 128 + ds * 32 + quad * 8];
            oa0[vt] = __builtin_amdgcn_mfma_f32_16x16x32_bf16(qs0[ds], bfrag, oa0[vt], 0, 0, 0);
            oa1[vt] = __builtin_amdgcn_mfma_f32_16x16x32_bf16(qs1[ds], bfrag, oa1[vt], 0, 0, 0);
        }
    // intra-chunk: P (LDS) * V
    const ushort* vbase = vT + (size_t)h * 128 * T_SEQ + t0;
    int ns0 = (tt0 + 2) >> 1, ns1 = (tt1 + 2) >> 1;
#pragma unroll
    for (int s32 = 0; s32 < 4; ++s32) {
        if (s32 < ns1) {
            bf16x8 af = *(const bf16x8*)&Ps[(tt1 * 16 + lane15) * 136 + s32 * 32 + quad * 8];
#pragma unroll
            for (int vt = 0; vt < 8; ++vt) {
                bf16x8 bfrag = *(const bf16x8*)&vbase[(size_t)(vt * 16 + lane15) * T_SEQ + s32 * 32 + quad * 8];
                oa1[vt] = __builtin_amdgcn_mfma_f32_16x16x32_bf16(af, bfrag, oa1[vt], 0, 0, 0);
            }
        }
    }
#pragma unroll
    for (int s32 = 0; s32 < 2; ++s32) {
        if (s32 < ns0) {
            bf16x8 af = *(const bf16x8*)&Ps[(tt0 * 16 + lane15) * 136 + s32 * 32 + quad * 8];
#pragma unroll
            for (int vt = 0; vt < 8; ++vt) {
                bf16x8 bfrag = *(const bf16x8*)&vbase[(size_t)(vt * 16 + lane15) * T_SEQ + s32 * 32 + quad * 8];
                oa0[vt] = __builtin_amdgcn_mfma_f32_16x16x32_bf16(af, bfrag, oa0[vt], 0, 0, 0);
            }
        }
    }
    // ---- epilogue ----
#pragma unroll
    for (int vt = 0; vt < 8; ++vt)
#pragma unroll
        for (int r = 0; r < 4; ++r) {
            o[(size_t)(t0 + tt0 * 16 + quad * 4 + r) * 2048 + h * 128 + vt * 16 + lane15] = oa0[vt][r];
            o[(size_t)(t0 + tt1 * 16 + quad * 4 + r) * 2048 + h * 128 + vt * 16 + lane15] = oa1[vt][r];
        }
}

// ---------------- group RMS-norm * g_norm_w * sigmoid-gate -> bf16 ----------------
__global__ __launch_bounds__(256) void gnorm_gate(const float* __restrict__ o,
                                                  const ushort* __restrict__ gate,
                                                  const float* __restrict__ gw,
                                                  ushort* __restrict__ gg) {
    int t = blockIdx.x;
    int tid = threadIdx.x;
    const float* op = o + (size_t)t * 2048;
    float4 xa = *(const float4*)(op + tid * 8);
    float4 xb = *(const float4*)(op + tid * 8 + 4);
    float x[8] = {xa.x, xa.y, xa.z, xa.w, xb.x, xb.y, xb.z, xb.w};
    float ss = 0.0f;
#pragma unroll
    for (int i = 0; i < 8; ++i) ss += x[i] * x[i];
#pragma unroll
    for (int off = 16; off > 0; off >>= 1) ss += __shfl_xor(ss, off);  // 32-thread group = 256 elems
    float r = rsqrtf(ss * (1.0f / 256.0f) + 1e-6f);
    const ushort* gp = gate + (size_t)t * 2048;
#pragma unroll
    for (int i = 0; i < 8; ++i) {
        int j = tid * 8 + i;
        float val = x[i] * r * gw[j] * bfu2f(gp[j]);
        gg[(size_t)t * 2048 + j] = f2bfu(val);
    }
}

extern "C" void kernel_launch(void* const* d_in, const int* in_sizes, int n_in,
                              void* d_out, int out_size, void* d_ws, size_t ws_size,
                              hipStream_t stream) {
    const int* positions   = (const int*)d_in[0];
    const float* hidden    = (const float*)d_in[1];
    const float* S0        = (const float*)d_in[2];
    const float* w_qkv     = (const float*)d_in[3];
    const float* w_g       = (const float*)d_in[4];
    const float* w_dense   = (const float*)d_in[5];
    const float* qw        = (const float*)d_in[6];
    const float* kw        = (const float*)d_in[7];
    const float* gw        = (const float*)d_in[8];

    char* ws = (char*)d_ws;
    ushort* qkv     = (ushort*)ws;                    // bf16 T x 6144            [0, 50331648)
    ushort* wqkv_t  = (ushort*)(ws + 50331648);       // bf16 6144 x 2048 (25.2M)
    ushort* wg_t    = (ushort*)(ws + 75497472);       // bf16 2048 x 2048 (8.4M)
    float*  PT      = (float*)(ws + 50331648);        // fp32 32x16x128x128 (33.6M) — aliases wqkv_t+wg_t (dead)
    ushort* wd_t    = (ushort*)(ws + 83886080);       // bf16 2048 x 2048 (8.4M)
    ushort* gatebuf = (ushort*)(ws + 92274688);       // bf16 T x 2048 (16.8M)
    ushort* hid_b   = (ushort*)(ws + 109051904);      // bf16 T x 2048 (16.8M)
    ushort* Spb     = (ushort*)(ws + 109051904);      // bf16 32x16x128x128 (16.8M) — aliases hid_b (dead)
    ushort* kT      = (ushort*)(ws + 125829120);      // bf16 16x128x4096 (16.8M)
    ushort* vT      = (ushort*)(ws + 142606336);      // bf16 16x128x4096 (16.8M)  total 159,383,552
    ushort* gg      = (ushort*)ws;                    // aliases qkv (dead by gnorm time)

    float* out  = (float*)d_out;
    float* Sfin = out + (size_t)T_SEQ * HID_C;
    float* obuf = out;                                // out-region doubles as attn scratch

    cvt_bf16<<<T_SEQ * HID_C / (256 * 8), 256, 0, stream>>>(hidden, hid_b, T_SEQ * HID_C);
    transpose_cvt<<<dim3(QKV_N / 64, HID_C / 64), 256, 0, stream>>>(w_qkv, wqkv_t, HID_C, QKV_N);
    transpose_cvt<<<dim3(HID_C / 64, HID_C / 64), 256, 0, stream>>>(w_g, wg_t, HID_C, HID_C);
    transpose_cvt<<<dim3(HID_C / 64, HID_C / 64), 256, 0, stream>>>(w_dense, wd_t, HID_C, HID_C);

    gemm_bt<0><<<dim3(QKV_N / 128, T_SEQ / 128), 256, 0, stream>>>(hid_b, wqkv_t, qkv, T_SEQ, QKV_N, HID_C);
    gemm_bt<1><<<dim3(HID_C / 128, T_SEQ / 128), 256, 0, stream>>>(hid_b, wg_t, gatebuf, T_SEQ, HID_C, HID_C);

    qk_post<<<T_SEQ, 256, 0, stream>>>(qkv, positions, qw, kw);
    transpose_kv<<<dim3(T_SEQ / 64, 2, NH * 2), 256, 0, stream>>>(qkv, kT, vT);

    chunk_partial<<<dim3(32, 16), 256, 0, stream>>>(kT, vT, PT);
    scan_states<<<2048, 128, 0, stream>>>(PT, S0, Spb, Sfin);
    chunk_out<<<dim3(32, 16), 256, 0, stream>>>(qkv, vT, Spb, obuf);
    gnorm_gate<<<T_SEQ, 256, 0, stream>>>(obuf, gatebuf, gw, gg);

    gemm_bt<2><<<dim3(HID_C / 128, T_SEQ / 128), 256, 0, stream>>>(gg, wd_t, out, T_SEQ, HID_C, HID_C);
}

// Round 4
// 485.515 us; speedup vs baseline: 1.2474x; 1.0393x over previous
//
#include <hip/hip_runtime.h>
#include <hip/hip_bf16.h>

using bf16x8 = __attribute__((ext_vector_type(8))) __bf16;
using f32x4  = __attribute__((ext_vector_type(4))) float;

constexpr int T_SEQ = 4096;
constexpr int HID_C = 2048;
constexpr int NH    = 16;
constexpr int QKV_N = 6144;

__device__ __forceinline__ float head_slope(int h) {
    // slope[h] = -2^{-(h+1)/2} * (1 - 1/31 + 1e-5)
    return -exp2f(-0.5f * (float)(h + 1)) * 0.967751935483871f;
}

__device__ __forceinline__ ushort f2bfu(float f) {
    __hip_bfloat16 h = __float2bfloat16(f);
    return *(ushort*)&h;
}
__device__ __forceinline__ float bfu2f(ushort u) {
    union { unsigned int i; float f; } x; x.i = ((unsigned int)u) << 16; return x.f;
}

// async global -> LDS, 16 bytes per lane; LDS dest = wave-uniform base + lane*16
__device__ __forceinline__ void async16(const ushort* g, ushort* l) {
    __builtin_amdgcn_global_load_lds((const __attribute__((address_space(1))) void*)g,
                                     (__attribute__((address_space(3))) void*)l, 16, 0, 0);
}

// ---------------- fp32 -> bf16 elementwise convert ----------------
__global__ __launch_bounds__(256) void cvt_bf16(const float* __restrict__ src,
                                                ushort* __restrict__ dst, int n) {
    int i = (blockIdx.x * 256 + threadIdx.x) * 8;
    if (i >= n) return;
    float4 a = *(const float4*)(src + i);
    float4 b = *(const float4*)(src + i + 4);
    ushort4 ua = {f2bfu(a.x), f2bfu(a.y), f2bfu(a.z), f2bfu(a.w)};
    ushort4 ub = {f2bfu(b.x), f2bfu(b.y), f2bfu(b.z), f2bfu(b.w)};
    *(ushort4*)(dst + i) = ua;
    *(ushort4*)(dst + i + 4) = ub;
}

// ---------------- fp32 [R,C] -> bf16 [C,R] transpose+convert (64x64 tiles) ----------------
__global__ __launch_bounds__(256) void transpose_cvt(const float* __restrict__ src,
                                                     ushort* __restrict__ dst,
                                                     int R, int C) {
    __shared__ ushort tile[64][68];
    int t = threadIdx.x;
    int tr = blockIdx.y * 64, tc = blockIdx.x * 64;
    int r0 = t >> 4;
    int c4 = (t & 15) << 2;
#pragma unroll
    for (int p = 0; p < 4; ++p) {
        int row = r0 + p * 16;
        float4 v = *(const float4*)&src[(size_t)(tr + row) * C + tc + c4];
        tile[row][c4 + 0] = f2bfu(v.x);
        tile[row][c4 + 1] = f2bfu(v.y);
        tile[row][c4 + 2] = f2bfu(v.z);
        tile[row][c4 + 3] = f2bfu(v.w);
    }
    __syncthreads();
#pragma unroll
    for (int p = 0; p < 4; ++p) {
        int orow = r0 + p * 16;
        ushort4 u;
        u.x = tile[c4 + 0][orow];
        u.y = tile[c4 + 1][orow];
        u.z = tile[c4 + 2][orow];
        u.w = tile[c4 + 3][orow];
        *(ushort4*)&dst[(size_t)(tc + orow) * R + tr + c4] = u;
    }
}

// ---------------- shared BK=64 MFMA GEMM core: acc += A[M,K] * Bt[N,K]^T tile ----------------
__device__ __forceinline__ void gemm_core(const ushort* __restrict__ A,
                                          const ushort* __restrict__ Bt,
                                          int K, int bm, int bn,
                                          ushort* As, ushort* Bs,
                                          f32x4 (&acc)[4][4]) {
    int tid = threadIdx.x;
    int lane = tid & 63, wave = tid >> 6;
    int lane15 = lane & 15, quad = lane >> 4;
    int wr = (wave & 1) * 64, wc = (wave >> 1) * 64;
    // DMA mapping: wave stages rows [wave*32, wave*32+32); lane = r_l*8 + g
    // physical group p of row r holds logical col-group p ^ (r&7)  (XOR swizzle)
    int r_l = lane >> 3;
    int g   = lane & 7;
    int colg = ((g ^ r_l) << 3);
    const ushort* gA = A + (size_t)(bm + wave * 32 + r_l) * K + colg;
    const ushort* gB = Bt + (size_t)(bn + wave * 32 + r_l) * K + colg;
    ushort* lA = As + (wave * 32) * 64;
    ushort* lB = Bs + (wave * 32) * 64;
    int sw = lane15 & 7;
    for (int k0 = 0; k0 < K; k0 += 64) {
#pragma unroll
        for (int d = 0; d < 4; ++d) {
            async16(gA + (size_t)d * 8 * K + k0, lA + d * 8 * 64);
            async16(gB + (size_t)d * 8 * K + k0, lB + d * 8 * 64);
        }
        __syncthreads();
#pragma unroll
        for (int ks = 0; ks < 2; ++ks) {
            bf16x8 af[4], bf[4];
#pragma unroll
            for (int i = 0; i < 4; ++i)
                af[i] = *(const bf16x8*)&As[(wr + i * 16 + lane15) * 64 + (((ks * 4 + quad) ^ sw) << 3)];
#pragma unroll
            for (int j = 0; j < 4; ++j)
                bf[j] = *(const bf16x8*)&Bs[(wc + j * 16 + lane15) * 64 + (((ks * 4 + quad) ^ sw) << 3)];
#pragma unroll
            for (int i = 0; i < 4; ++i)
#pragma unroll
                for (int j = 0; j < 4; ++j)
                    acc[i][j] = __builtin_amdgcn_mfma_f32_16x16x32_bf16(af[i], bf[j], acc[i][j], 0, 0, 0);
        }
        __syncthreads();
    }
}

// ---- fused qkv+gate GEMM: Bcat = [wqkv_t ; wg_t] (8192 x K). cols<6144 -> qkv, else sigmoid -> gate ----
__global__ __launch_bounds__(256) void gemm_fused(const ushort* __restrict__ A,
                                                  const ushort* __restrict__ Bcat,
                                                  ushort* __restrict__ qkv,
                                                  ushort* __restrict__ gate, int K) {
    __shared__ ushort As[128 * 64];
    __shared__ ushort Bs[128 * 64];
    int bm = blockIdx.y * 128, bn = blockIdx.x * 128;
    f32x4 acc[4][4] = {};
    gemm_core(A, Bcat, K, bm, bn, As, Bs, acc);
    int lane = threadIdx.x & 63, wave = threadIdx.x >> 6;
    int lane15 = lane & 15, quad = lane >> 4;
    int wr = (wave & 1) * 64, wc = (wave >> 1) * 64;
    bool isg = bn >= QKV_N;
    ushort* outp = isg ? gate : qkv;
    int ncol = isg ? HID_C : QKV_N;
    int cb = isg ? bn - QKV_N : bn;
#pragma unroll
    for (int i = 0; i < 4; ++i)
#pragma unroll
        for (int j = 0; j < 4; ++j) {
            int rbase = bm + wr + i * 16 + quad * 4;
            int col = cb + wc + j * 16 + lane15;
#pragma unroll
            for (int r = 0; r < 4; ++r) {
                float v = acc[i][j][r];
                if (isg) v = 1.0f / (1.0f + __expf(-v));
                outp[(size_t)(rbase + r) * ncol + col] = f2bfu(v);
            }
        }
}

// ---- dense GEMM: fp32 out ----
__global__ __launch_bounds__(256) void gemm_dense(const ushort* __restrict__ A,
                                                  const ushort* __restrict__ Bt,
                                                  float* __restrict__ Cout, int N, int K) {
    __shared__ ushort As[128 * 64];
    __shared__ ushort Bs[128 * 64];
    int bm = blockIdx.y * 128, bn = blockIdx.x * 128;
    f32x4 acc[4][4] = {};
    gemm_core(A, Bt, K, bm, bn, As, Bs, acc);
    int lane = threadIdx.x & 63, wave = threadIdx.x >> 6;
    int lane15 = lane & 15, quad = lane >> 4;
    int wr = (wave & 1) * 64, wc = (wave >> 1) * 64;
#pragma unroll
    for (int i = 0; i < 4; ++i)
#pragma unroll
        for (int j = 0; j < 4; ++j) {
            int rbase = bm + wr + i * 16 + quad * 4;
            int col = bn + wc + j * 16 + lane15;
#pragma unroll
            for (int r = 0; r < 4; ++r)
                Cout[(size_t)(rbase + r) * N + col] = acc[i][j][r];
        }
}

// ---------------- rope table: tab[t][fi] = (cos, sin) of pos_t * 10000^(-fi/32) ----------------
__global__ __launch_bounds__(256) void rope_tab(const int* __restrict__ positions,
                                                float2* __restrict__ tab) {
    int i = blockIdx.x * 256 + threadIdx.x;   // i < T*32
    int t = i >> 5, fi = i & 31;
    float inv = expf((float)fi * -0.2878231366f);   // ln(10000)/32
    float freq = (float)positions[t] * inv;
    float sn, cs;
    sincosf(freq, &sn, &cs);
    tab[i] = make_float2(cs, sn);
}

// ---- fused q/k RMSNorm + RoPE (+q scale) and k/v transpose.  y: kind = y>>4 (0=q,1=k,2=v), h = y&15 ----
__global__ __launch_bounds__(256) void qk_rope_T(ushort* __restrict__ qkv,
                                                 const float2* __restrict__ tab,
                                                 const float* __restrict__ qw,
                                                 const float* __restrict__ kw,
                                                 ushort* __restrict__ kT,
                                                 ushort* __restrict__ vT) {
    __shared__ ushort tile[64][132];
    int bt = blockIdx.x;
    int kind = blockIdx.y >> 4, h = blockIdx.y & 15;
    int tid = threadIdx.x;
    int row = tid >> 2, c = tid & 3, d0 = c * 32;
    int t = bt * 64 + row;
    ushort* base = qkv + (size_t)t * QKV_N + kind * 2048 + h * 128 + d0;
    bf16x8 pk[4];
#pragma unroll
    for (int p = 0; p < 4; ++p) pk[p] = *(const bf16x8*)(base + p * 8);
    if (kind < 2) {
        float x[32];
        float ss = 0.f;
#pragma unroll
        for (int p = 0; p < 4; ++p)
#pragma unroll
            for (int i = 0; i < 8; ++i) {
                x[p * 8 + i] = (float)pk[p][i];
                ss += x[p * 8 + i] * x[p * 8 + i];
            }
        ss += __shfl_xor(ss, 1);
        ss += __shfl_xor(ss, 2);
        float rr = rsqrtf(ss * (1.0f / 128.0f) + 1e-6f);
        const float* w = (kind == 0) ? qw : kw;
#pragma unroll
        for (int i = 0; i < 32; ++i) x[i] *= rr * w[d0 + i];
        // rope on d<64: c=0 holds x1 (d 0..31), c=1 holds x2 (d 32..63); partner via xor 1
#pragma unroll
        for (int i = 0; i < 32; ++i) {
            float p = __shfl_xor(x[i], 1);
            if (c < 2) {
                float2 rt = tab[t * 32 + i];
                x[i] = (c == 0) ? (x[i] * rt.x - p * rt.y) : (x[i] * rt.x + p * rt.y);
            }
        }
        float sc = (kind == 0) ? 0.08838834764831845f : 1.0f;   // 128^-0.5 on q
#pragma unroll
        for (int p = 0; p < 4; ++p)
#pragma unroll
            for (int i = 0; i < 8; ++i) pk[p][i] = (__bf16)(x[p * 8 + i] * sc);
#pragma unroll
        for (int p = 0; p < 4; ++p) *(bf16x8*)(base + p * 8) = pk[p];
    }
    if (kind >= 1) {
        // transpose 64t x 128d -> out[d][t]
#pragma unroll
        for (int p = 0; p < 4; ++p) {
            ushort4* s = (ushort4*)&pk[p];
            *(ushort4*)&tile[row][d0 + p * 8]     = s[0];
            *(ushort4*)&tile[row][d0 + p * 8 + 4] = s[1];
        }
        __syncthreads();
        ushort* outT = ((kind == 1) ? kT : vT) + (size_t)(h * 128) * T_SEQ + bt * 64;
        int d = tid >> 1, half = tid & 1;
#pragma unroll
        for (int tt = 0; tt < 8; ++tt) {
            int tl = half * 32 + tt * 4;
            ushort4 u;
            u.x = tile[tl + 0][d];
            u.y = tile[tl + 1][d];
            u.z = tile[tl + 2][d];
            u.w = tile[tl + 3][d];
            *(ushort4*)&outT[(size_t)d * T_SEQ + tl] = u;
        }
    }
}

// ------- per-chunk partial state (transposed): PT[c,h][v][d] = sum_j lam^(127-j) v_j[v] k_j[d] -------
__global__ __launch_bounds__(256) void chunk_partial(const ushort* __restrict__ kT,
                                                     const ushort* __restrict__ vT,
                                                     float* __restrict__ PT) {
    int c = blockIdx.x, h = blockIdx.y;
    float slope = head_slope(h);
    float lam_inv = __expf(-slope);
    int tid = threadIdx.x, lane = tid & 63, wave = tid >> 6;
    int lane15 = lane & 15, quad = lane >> 4;
    int wv = (wave & 1) * 64, wd = (wave >> 1) * 64;
    const ushort* vbase = vT + (size_t)h * 128 * T_SEQ + c * 128;
    const ushort* kbase = kT + (size_t)h * 128 * T_SEQ + c * 128;
    f32x4 acc[4][4] = {};
#pragma unroll
    for (int j0 = 0; j0 < 128; j0 += 32) {
        float w8[8];
        w8[0] = __expf(slope * (float)(127 - (j0 + quad * 8)));
#pragma unroll
        for (int kk = 1; kk < 8; ++kk) w8[kk] = w8[kk - 1] * lam_inv;
        bf16x8 afr[4], bfr[4];
#pragma unroll
        for (int i = 0; i < 4; ++i) {
            bf16x8 v = *(const bf16x8*)&vbase[(size_t)(wv + i * 16 + lane15) * T_SEQ + j0 + quad * 8];
#pragma unroll
            for (int kk = 0; kk < 8; ++kk) afr[i][kk] = (__bf16)((float)v[kk] * w8[kk]);
        }
#pragma unroll
        for (int j = 0; j < 4; ++j)
            bfr[j] = *(const bf16x8*)&kbase[(size_t)(wd + j * 16 + lane15) * T_SEQ + j0 + quad * 8];
#pragma unroll
        for (int i = 0; i < 4; ++i)
#pragma unroll
            for (int j = 0; j < 4; ++j)
                acc[i][j] = __builtin_amdgcn_mfma_f32_16x16x32_bf16(afr[i], bfr[j], acc[i][j], 0, 0, 0);
    }
    float* out = PT + ((size_t)c * 16 + h) * 16384;
#pragma unroll
    for (int i = 0; i < 4; ++i)
#pragma unroll
        for (int j = 0; j < 4; ++j)
#pragma unroll
            for (int r = 0; r < 4; ++r)
                out[(size_t)(wv + i * 16 + quad * 4 + r) * 128 + wd + j * 16 + lane15] = acc[i][j][r];
}

// ------- sequential scan over 32 chunks: PT -> Spb (bf16 prefix states) + Sfin -------
__global__ __launch_bounds__(128) void scan_states(const float* __restrict__ PT,
                                                   const float* __restrict__ S0,
                                                   ushort* __restrict__ Spb,
                                                   float* __restrict__ Sfin) {
    int hv = blockIdx.x;              // h*128 + v
    int d = threadIdx.x;              // k-dim
    int h = hv >> 7, v = hv & 127;
    float lamC = __expf(head_slope(h) * 128.0f);
    float s = S0[(size_t)h * 16384 + d * 128 + v];
#pragma unroll
    for (int c = 0; c < 32; ++c) {
        size_t idx = ((size_t)c * 2048 + hv) * 128 + d;
        Spb[idx] = f2bfu(s);          // state BEFORE chunk c, layout [c][h][v][d]
        s = s * lamC + PT[idx];
    }
    Sfin[(size_t)h * 16384 + d * 128 + v] = s;
}

// ------- per-chunk output: QK^T (masked/decayed) * V + lam^(t+1) * Q * S_prev -------
__global__ __launch_bounds__(256) void chunk_out(const ushort* __restrict__ qkv,
                                                 const ushort* __restrict__ vT,
                                                 const ushort* __restrict__ Spb,
                                                 ushort* __restrict__ o) {
    int c = blockIdx.x, h = blockIdx.y;
    float slope = head_slope(h);
    __shared__ ushort Ps[128 * 136];   // padded: row stride 272B -> conflict-free b128
    int tid = threadIdx.x, lane = tid & 63, wave = tid >> 6;
    int lane15 = lane & 15, quad = lane >> 4;
    int t0 = c * 128;
    int tt0 = wave, tt1 = 7 - wave;    // owned t-tiles (balanced triangular split)
    const ushort* qbase = qkv + (size_t)t0 * QKV_N + h * 128;
    const ushort* kbase = qbase + 2048;

    bf16x8 qf0[4], qf1[4];
#pragma unroll
    for (int ds = 0; ds < 4; ++ds) {
        qf0[ds] = *(const bf16x8*)&qbase[(size_t)(tt0 * 16 + lane15) * QKV_N + ds * 32 + quad * 8];
        qf1[ds] = *(const bf16x8*)&qbase[(size_t)(tt1 * 16 + lane15) * QKV_N + ds * 32 + quad * 8];
    }
    // ---- phase 1: scores ----
    f32x4 s0a[4] = {};
    f32x4 s1a[8] = {};
#pragma unroll
    for (int st = 0; st < 8; ++st) {
        if (st <= tt1) {
            bf16x8 kf[4];
#pragma unroll
            for (int ds = 0; ds < 4; ++ds)
                kf[ds] = *(const bf16x8*)&kbase[(size_t)(st * 16 + lane15) * QKV_N + ds * 32 + quad * 8];
#pragma unroll
            for (int ds = 0; ds < 4; ++ds)
                s1a[st] = __builtin_amdgcn_mfma_f32_16x16x32_bf16(qf1[ds], kf[ds], s1a[st], 0, 0, 0);
            if (st <= tt0) {
#pragma unroll
                for (int ds = 0; ds < 4; ++ds)
                    s0a[st] = __builtin_amdgcn_mfma_f32_16x16x32_bf16(qf0[ds], kf[ds], s0a[st], 0, 0, 0);
            }
        }
    }
    // ---- park masked/decayed scores (zero strip pads odd 16-blocks to 32) ----
    int stmax0 = tt0 + ((tt0 & 1) ? 0 : 1);
    int stmax1 = tt1 + ((tt1 & 1) ? 0 : 1);
#pragma unroll
    for (int st = 0; st < 8; ++st) {
        if (st <= stmax1) {
#pragma unroll
            for (int r = 0; r < 4; ++r) {
                int t = tt1 * 16 + quad * 4 + r;
                int s = st * 16 + lane15;
                float val = 0.f;
                if (st <= tt1) val = (s <= t) ? s1a[st][r] * __expf(slope * (float)(t - s)) : 0.f;
                Ps[t * 136 + s] = f2bfu(val);
            }
        }
    }
#pragma unroll
    for (int st = 0; st < 5; ++st) {
        if (st <= stmax0) {
#pragma unroll
            for (int r = 0; r < 4; ++r) {
                int t = tt0 * 16 + quad * 4 + r;
                int s = st * 16 + lane15;
                float val = 0.f;
                if (st <= tt0) val = (s <= t) ? s0a[st][r] * __expf(slope * (float)(t - s)) : 0.f;
                Ps[t * 136 + s] = f2bfu(val);
            }
        }
    }
    __syncthreads();
    // ---- phase 2: O = P*V + diag(lam^(t+1)) Q*S_prev ----
    f32x4 oa0[8] = {};
    f32x4 oa1[8] = {};
    float lam0 = __expf(slope * (float)(tt0 * 16 + lane15 + 1));
    float lam1 = __expf(slope * (float)(tt1 * 16 + lane15 + 1));
    bf16x8 qs0[4], qs1[4];
#pragma unroll
    for (int ds = 0; ds < 4; ++ds)
#pragma unroll
        for (int kk = 0; kk < 8; ++kk) {
            qs0[ds][kk] = (__bf16)((float)qf0[ds][kk] * lam0);
            qs1[ds][kk] = (__bf16)((float)qf1[ds][kk] * lam1);
        }
    const ushort* spb = Spb + ((size_t)c * 2048 + h * 128) * 128;
#pragma unroll
    for (int vt = 0; vt < 8; ++vt)
#pragma unroll
        for (int ds = 0; ds < 4; ++ds) {
            bf16x8 bfrag = *(const bf16x8*)&spb[(vt * 16 + lane15) * 128 + ds * 32 + quad * 8];
            oa0[vt] = __builtin_amdgcn_mfma_f32_16x16x32_bf16(qs0[ds], bfrag, oa0[vt], 0, 0, 0);
            oa1[vt] = __builtin_amdgcn_mfma_f32_16x16x32_bf16(qs1[ds], bfrag, oa1[vt], 0, 0, 0);
        }
    const ushort* vbase = vT + (size_t)h * 128 * T_SEQ + t0;
    int ns0 = (tt0 + 2) >> 1, ns1 = (tt1 + 2) >> 1;
#pragma unroll
    for (int s32 = 0; s32 < 4; ++s32) {
        if (s32 < ns1) {
            bf16x8 af = *(const bf16x8*)&Ps[(tt1 * 16 + lane15) * 136 + s32 * 32 + quad * 8];
#pragma unroll
            for (int vt = 0; vt < 8; ++vt) {
                bf16x8 bfrag = *(const bf16x8*)&vbase[(size_t)(vt * 16 + lane15) * T_SEQ + s32 * 32 + quad * 8];
                oa1[vt] = __builtin_amdgcn_mfma_f32_16x16x32_bf16(af, bfrag, oa1[vt], 0, 0, 0);
            }
        }
    }
#pragma unroll
    for (int s32 = 0; s32 < 2; ++s32) {
        if (s32 < ns0) {
            bf16x8 af = *(const bf16x8*)&Ps[(tt0 * 16 + lane15) * 136 + s32 * 32 + quad * 8];
#pragma unroll
            for (int vt = 0; vt < 8; ++vt) {
                bf16x8 bfrag = *(const bf16x8*)&vbase[(size_t)(vt * 16 + lane15) * T_SEQ + s32 * 32 + quad * 8];
                oa0[vt] = __builtin_amdgcn_mfma_f32_16x16x32_bf16(af, bfrag, oa0[vt], 0, 0, 0);
            }
        }
    }
    // ---- epilogue (bf16) ----
#pragma unroll
    for (int vt = 0; vt < 8; ++vt)
#pragma unroll
        for (int r = 0; r < 4; ++r) {
            o[(size_t)(t0 + tt0 * 16 + quad * 4 + r) * 2048 + h * 128 + vt * 16 + lane15] = f2bfu(oa0[vt][r]);
            o[(size_t)(t0 + tt1 * 16 + quad * 4 + r) * 2048 + h * 128 + vt * 16 + lane15] = f2bfu(oa1[vt][r]);
        }
}

// ---------------- group RMS-norm * g_norm_w * sigmoid-gate -> bf16 ----------------
__global__ __launch_bounds__(256) void gnorm_gate(const ushort* __restrict__ o,
                                                  const ushort* __restrict__ gate,
                                                  const float* __restrict__ gw,
                                                  ushort* __restrict__ gg) {
    int t = blockIdx.x;
    int tid = threadIdx.x;
    const ushort* op = o + (size_t)t * 2048 + tid * 8;
    bf16x8 xv = *(const bf16x8*)op;
    float x[8];
    float ss = 0.0f;
#pragma unroll
    for (int i = 0; i < 8; ++i) { x[i] = (float)xv[i]; ss += x[i] * x[i]; }
#pragma unroll
    for (int off = 16; off > 0; off >>= 1) ss += __shfl_xor(ss, off);  // 32-thread group = 256 elems
    float r = rsqrtf(ss * (1.0f / 256.0f) + 1e-6f);
    const ushort* gp = gate + (size_t)t * 2048;
#pragma unroll
    for (int i = 0; i < 8; ++i) {
        int j = tid * 8 + i;
        float val = x[i] * r * gw[j] * bfu2f(gp[j]);
        gg[(size_t)t * 2048 + j] = f2bfu(val);
    }
}

extern "C" void kernel_launch(void* const* d_in, const int* in_sizes, int n_in,
                              void* d_out, int out_size, void* d_ws, size_t ws_size,
                              hipStream_t stream) {
    const int* positions   = (const int*)d_in[0];
    const float* hidden    = (const float*)d_in[1];
    const float* S0        = (const float*)d_in[2];
    const float* w_qkv     = (const float*)d_in[3];
    const float* w_g       = (const float*)d_in[4];
    const float* w_dense   = (const float*)d_in[5];
    const float* qw        = (const float*)d_in[6];
    const float* kw        = (const float*)d_in[7];
    const float* gw        = (const float*)d_in[8];

    char* ws = (char*)d_ws;
    ushort* qkv     = (ushort*)ws;                    // bf16 T x 6144            [0, 50331648)
    ushort* wqkv_t  = (ushort*)(ws + 50331648);       // bf16 6144 x 2048 (25.2M) — Bcat rows 0..6143
    ushort* wg_t    = (ushort*)(ws + 75497472);       // bf16 2048 x 2048 (8.4M)  — Bcat rows 6144..8191
    float2* ropet   = (float2*)(ws + 50331648);       // 1 MB — aliases wqkv_t (dead after gemm_fused)
    float*  PT      = (float*)(ws + 50331648);        // fp32 32x16x128x128 (33.6M) — aliases both (dead)
    ushort* wd_t    = (ushort*)(ws + 83886080);       // bf16 2048 x 2048 (8.4M)
    ushort* gatebuf = (ushort*)(ws + 92274688);       // bf16 T x 2048 (16.8M)
    ushort* hid_b   = (ushort*)(ws + 109051904);      // bf16 T x 2048 (16.8M)
    ushort* Spb     = (ushort*)(ws + 109051904);      // bf16 32x16x128x128 (16.8M) — aliases hid_b (dead)
    ushort* kT      = (ushort*)(ws + 125829120);      // bf16 16x128x4096 (16.8M)
    ushort* vT      = (ushort*)(ws + 142606336);      // bf16 16x128x4096 (16.8M)  total 159,383,552
    ushort* gg      = (ushort*)ws;                    // aliases qkv (dead by gnorm time)

    float* out  = (float*)d_out;
    float* Sfin = out + (size_t)T_SEQ * HID_C;
    ushort* obuf = (ushort*)d_out;                    // out-region doubles as bf16 attn scratch

    cvt_bf16<<<T_SEQ * HID_C / (256 * 8), 256, 0, stream>>>(hidden, hid_b, T_SEQ * HID_C);
    transpose_cvt<<<dim3(QKV_N / 64, HID_C / 64), 256, 0, stream>>>(w_qkv, wqkv_t, HID_C, QKV_N);
    transpose_cvt<<<dim3(HID_C / 64, HID_C / 64), 256, 0, stream>>>(w_g, wg_t, HID_C, HID_C);
    transpose_cvt<<<dim3(HID_C / 64, HID_C / 64), 256, 0, stream>>>(w_dense, wd_t, HID_C, HID_C);

    gemm_fused<<<dim3((QKV_N + HID_C) / 128, T_SEQ / 128), 256, 0, stream>>>(hid_b, wqkv_t, qkv, gatebuf, HID_C);

    rope_tab<<<T_SEQ * 32 / 256, 256, 0, stream>>>(positions, ropet);
    qk_rope_T<<<dim3(T_SEQ / 64, 48), 256, 0, stream>>>(qkv, ropet, qw, kw, kT, vT);

    chunk_partial<<<dim3(32, 16), 256, 0, stream>>>(kT, vT, PT);
    scan_states<<<2048, 128, 0, stream>>>(PT, S0, Spb, Sfin);
    chunk_out<<<dim3(32, 16), 256, 0, stream>>>(qkv, vT, Spb, obuf);
    gnorm_gate<<<T_SEQ, 256, 0, stream>>>(obuf, gatebuf, gw, gg);

    gemm_dense<<<dim3(HID_C / 128, T_SEQ / 128), 256, 0, stream>>>(gg, wd_t, out, HID_C, HID_C);
}